// Round 7
// baseline (277.352 us; speedup 1.0000x reference)
//
#include <hip/hip_runtime.h>
#include <hip/hip_bf16.h>

#define TOKENS 2048
#define HIDDEN 1024
#define NEXP   8
#define INTER  2816
#define N1     5632      // 2*INTER
#define ROWCAP 6144      // 256-pad worst case: 4096 + 8*255 = 6136
#define MT     24        // ROWCAP/256 m-tiles
#define NT1    44        // gemm1 col tiles (64 gate + 64 up cols)
#define NT2    8         // gemm2 col tiles (128 out cols)
#define SPLITK 2         // gemm2 K-slices

typedef __attribute__((ext_vector_type(8))) short short8;   // 8 bf16 (MFMA A/B frag)
typedef __attribute__((ext_vector_type(4))) float f32x4;    // MFMA C/D frag

typedef unsigned int __attribute__((address_space(1))) as1_uint;
typedef unsigned int __attribute__((address_space(3))) as3_uint;

__device__ __forceinline__ void gload16(const void* g, void* l) {
  // async global->LDS, 16B/lane, LDS dest = wave-uniform base + lane*16
  __builtin_amdgcn_global_load_lds((const as1_uint*)g, (as3_uint*)l, 16, 0, 0);
}

__device__ __forceinline__ unsigned short f2bf(float f) {  // RNE f32->bf16 (bit trick)
  unsigned u = __float_as_uint(f);
  u += 0x7fff + ((u >> 16) & 1);
  return (unsigned short)(u >> 16);
}
__device__ __forceinline__ float bf2f(unsigned short h) {
  return __uint_as_float(((unsigned)h) << 16);
}
__device__ __forceinline__ unsigned short bfs(float x) {   // compiler fuses pairs -> v_cvt_pk_bf16_f32
  __hip_bfloat16 h = __float2bfloat16(x);
  return *reinterpret_cast<unsigned short*>(&h);
}
__device__ __forceinline__ short8 pack8(f32x4 lo, f32x4 hi) {  // 8 f32 -> bf16 frag
  short8 o;
  o[0] = (short)bfs(lo[0]); o[1] = (short)bfs(lo[1]); o[2] = (short)bfs(lo[2]); o[3] = (short)bfs(lo[3]);
  o[4] = (short)bfs(hi[0]); o[5] = (short)bfs(hi[1]); o[6] = (short)bfs(hi[2]); o[7] = (short)bfs(hi[3]);
  return o;
}

// ---------------- routing: softmax->top2->renorm == sigmoid(l0-l1) ----------------
__global__ void k_routing(const float* __restrict__ gate, int* __restrict__ ctrl,
                          int* __restrict__ tkid, float* __restrict__ tkw) {
  int t = blockIdx.x * blockDim.x + threadIdx.x;
  if (t >= TOKENS) return;
  float l[8];
#pragma unroll
  for (int i = 0; i < 8; i++) l[i] = gate[t * 8 + i];
  int i0 = 0; float m0 = l[0];
#pragma unroll
  for (int i = 1; i < 8; i++) if (l[i] > m0) { m0 = l[i]; i0 = i; }
  int i1 = -1; float m1 = -3.4e38f;
#pragma unroll
  for (int i = 0; i < 8; i++) if (i != i0 && l[i] > m1) { m1 = l[i]; i1 = i; }
  float e  = __expf(m1 - m0);
  float w0 = 1.f / (1.f + e);
  float w1 = e / (1.f + e);
  tkid[2 * t] = i0; tkid[2 * t + 1] = i1;
  tkw[2 * t] = w0;  tkw[2 * t + 1] = w1;
  atomicAdd(&ctrl[i0], 1);
  atomicAdd(&ctrl[i1], 1);
}

// ctrl (ints): [0..7]=cnt  [8..15]=cursor  [16..23]=base (256-aligned prefix)
__global__ void k_base(int* ctrl) {
  if (threadIdx.x == 0) {
    int a = 0;
    for (int e = 0; e < 8; e++) { ctrl[16 + e] = a; a += ((ctrl[e] + 255) >> 8) << 8; }
  }
}

__global__ void k_fill(int* __restrict__ ctrl, const int* __restrict__ tkid,
                       int* __restrict__ rtok, int* __restrict__ trow) {
  int t = blockIdx.x * blockDim.x + threadIdx.x;
  if (t >= TOKENS) return;
#pragma unroll
  for (int k = 0; k < 2; k++) {
    int e = tkid[2 * t + k];
    int pos = atomicAdd(&ctrl[8 + e], 1);
    int row = ctrl[16 + e] + pos;
    rtok[row] = t;
    trow[2 * t + k] = row;
  }
}

// gather x rows (f32) -> bf16 A ordered by expert segment; zero padded rows
__global__ void k_gather(const float* __restrict__ x, const int* __restrict__ ctrl,
                         const int* __restrict__ rtok, unsigned short* __restrict__ Abf) {
  int row = blockIdx.x;
  int e = -1, local = 0;
  for (int i = 0; i < 8; i++) {
    int b = ctrl[16 + i], p = ((ctrl[i] + 255) >> 8) << 8;
    if (row >= b && row < b + p) { e = i; local = row - b; break; }
  }
  if (e < 0) return;
  int tid = threadIdx.x;
  unsigned short* dst = Abf + (size_t)row * HIDDEN;
  if (local < ctrl[e]) {
    int t = rtok[row];
    float4 v = ((const float4*)(x + (size_t)t * HIDDEN))[tid];
    ushort4 o; o.x = f2bf(v.x); o.y = f2bf(v.y); o.z = f2bf(v.z); o.w = f2bf(v.w);
    ((ushort4*)dst)[tid] = o;
  } else {
    ushort4 z; z.x = 0; z.y = 0; z.z = 0; z.w = 0;
    ((ushort4*)dst)[tid] = z;
  }
}

__device__ __forceinline__ int tile_lookup(const int* ctrl, int mt, int* ml) {
  int a0 = 0;
  for (int i = 0; i < 8; i++) {
    int pt = (ctrl[i] + 255) >> 8;
    if (mt < a0 + pt) { *ml = mt - a0; return i; }
    a0 += pt;
  }
  return -1;
}

// ============ GEMM1: 256x128 tile, double-buffered LDS, prefetch-next-under-MFMA ========
// A [256][64] bf16 (32K, 8-deep XOR swz); B [128][64] f32 (32K, 16-deep XOR swz).
// dbuf 128KB -> 1 block/CU (8 waves, 2/SIMD); pipeline hides staging (T3 minimum 2-phase).
__global__ __launch_bounds__(512, 2) void k_gemm1(const float* __restrict__ w1,
    const unsigned short* __restrict__ Abf, unsigned short* __restrict__ act,
    const int* __restrict__ ctrl) {
  union __align__(16) LdsU {
    struct { unsigned char A0[32768]; unsigned char Bf0[32768];
             unsigned char A1[32768]; unsigned char Bf1[32768]; } st;
    unsigned short hb[256 * 132];   // 67584 B
  };
  __shared__ LdsU lds;
  int bid = blockIdx.x;                        // 1056 % 8 == 0, bijective XCD swizzle
  int wg = (bid & 7) * (NT1 * MT / 8) + (bid >> 3);
  int nt = wg / MT, mt = wg % MT;              // nt-major: XCD chunk shares B panel
  int ml; int e = tile_lookup(ctrl, mt, &ml);
  if (e < 0) return;
  int tid = threadIdx.x, lane = tid & 63, wid = tid >> 6, wr = wid >> 1, wc = wid & 1;
  int rbase = ctrl[16 + e] + ml * 256;
  const unsigned char* Ab = (const unsigned char*)(Abf + (size_t)rbase * HIDDEN);
  const unsigned char* Bw = (const unsigned char*)(w1 + (size_t)e * N1 * HIDDEN);
  int l3 = lane >> 3, l4 = lane >> 4, l15 = lane & 15;
  int swzA = ((lane & 7) ^ l3) << 4;

  unsigned aoff[4], boff[4];
#pragma unroll
  for (int i = 0; i < 4; i++) {
    int g = wid * 4 + i;                       // 32 groups of 8 A-rows (0..255)
    aoff[i] = (unsigned)(g * 8 + l3) * (HIDDEN * 2) + swzA;
  }
#pragma unroll
  for (int i = 0; i < 4; i++) {
    int r = (wid * 4 + i) * 4 + l4;            // 32 groups of 4 f32 B-rows (0..127)
    int grow = (r < 64) ? nt * 64 + r : INTER + nt * 64 + (r - 64);
    boff[i] = (unsigned)grow * (HIDDEN * 4) + ((l15 ^ (r & 15)) << 4);  // pre-swizzled src
  }

  f32x4 acc[4][4];
  f32x4 zero = {0.f, 0.f, 0.f, 0.f};
#pragma unroll
  for (int i = 0; i < 4; i++)
#pragma unroll
    for (int j = 0; j < 4; j++) acc[i][j] = zero;

#define STG1(kk, Ad, Bd) do {                                                        \
  _Pragma("unroll") for (int i = 0; i < 4; i++)                                      \
    gload16(Ab + (size_t)aoff[i] + (kk) * 128, &(Ad)[(wid * 4 + i) * 1024]);         \
  _Pragma("unroll") for (int i = 0; i < 4; i++)                                      \
    gload16(Bw + (size_t)boff[i] + (kk) * 256, &(Bd)[(wid * 4 + i) * 1024]);         \
} while (0)

#define CMP1(Ad, Bd) do {                                                            \
  _Pragma("unroll") for (int ks = 0; ks < 2; ++ks) {                                 \
    short8 a[4], b[4];                                                               \
    _Pragma("unroll") for (int mi = 0; mi < 4; mi++) {                               \
      int row = wr * 64 + mi * 16 + l15;                                             \
      int koff = ks * 64 + (l4 << 4);                                                \
      a[mi] = *(const short8*)&(Ad)[row * 128 + (koff ^ ((row & 7) << 4))];          \
    }                                                                                \
    _Pragma("unroll") for (int ni = 0; ni < 4; ni++) {                               \
      int r = wc * 64 + ni * 16 + l15;                                               \
      int c = ks * 8 + l4 * 2;                                                       \
      f32x4 lo = *(const f32x4*)&(Bd)[r * 256 + ((c ^ (r & 15)) << 4)];              \
      f32x4 hi = *(const f32x4*)&(Bd)[r * 256 + (((c + 1) ^ (r & 15)) << 4)];        \
      b[ni] = pack8(lo, hi);                                                         \
    }                                                                                \
    _Pragma("unroll") for (int mi = 0; mi < 4; mi++)                                 \
      _Pragma("unroll") for (int ni = 0; ni < 4; ni++)                               \
        acc[mi][ni] = __builtin_amdgcn_mfma_f32_16x16x32_bf16(a[mi], b[ni], acc[mi][ni], 0, 0, 0); \
  }                                                                                  \
} while (0)

  const int NS = HIDDEN / 64;                  // 16, even
  STG1(0, lds.st.A0, lds.st.Bf0);
  __syncthreads();
  for (int s = 0; s < NS; s += 2) {
    STG1(s + 1, lds.st.A1, lds.st.Bf1);        // prefetch flies under compute(buf0)
    CMP1(lds.st.A0, lds.st.Bf0);
    __syncthreads();                           // vmcnt(0)+barrier: buf1 ready
    if (s + 2 < NS) STG1(s + 2, lds.st.A0, lds.st.Bf0);
    CMP1(lds.st.A1, lds.st.Bf1);
    __syncthreads();
  }
#undef STG1
#undef CMP1

  // epilogue: h -> LDS bf16, then act = silu(gate)*up -> global
#pragma unroll
  for (int mi = 0; mi < 4; mi++)
#pragma unroll
    for (int ni = 0; ni < 4; ni++)
#pragma unroll
      for (int r = 0; r < 4; r++) {
        int row = wr * 64 + mi * 16 + (l4 << 2) + r;   // C/D: row=(lane>>4)*4+reg
        int col = wc * 64 + ni * 16 + l15;             //      col=lane&15
        lds.hb[row * 132 + col] = f2bf(acc[mi][ni][r]);
      }
  __syncthreads();
  {
    int r = tid >> 1, ch = (tid & 1) * 32;
    unsigned short* orow = act + (size_t)(rbase + r) * INTER + nt * 64 + ch;
    const unsigned short* hrow = &lds.hb[r * 132];
#pragma unroll
    for (int j = 0; j < 32; j += 4) {
      ushort4 o;
#pragma unroll
      for (int q = 0; q < 4; q++) {
        float g = bf2f(hrow[ch + j + q]);
        float u = bf2f(hrow[64 + ch + j + q]);
        float s = g / (1.f + __expf(-g));
        ((unsigned short*)&o)[q] = f2bf(s * u);
      }
      *(ushort4*)(orow + j) = o;
    }
  }
}

// ============ GEMM2: 256x128 tile, same dbuf pipeline, split-K, plain f32 stores ========
__global__ __launch_bounds__(512, 2) void k_gemm2(const float* __restrict__ w2,
    const unsigned short* __restrict__ act, float* __restrict__ Pb,
    const int* __restrict__ ctrl) {
  struct __align__(16) Lds2 { unsigned char A0[32768]; unsigned char Bf0[32768];
                              unsigned char A1[32768]; unsigned char Bf1[32768]; };
  __shared__ Lds2 lds;
  int bid = blockIdx.x;                        // 384 % 8 == 0
  int wg = (bid & 7) * (NT2 * MT * SPLITK / 8) + (bid >> 3);
  int mt = wg % MT;
  int p = wg / MT;                             // 0..15
  int z = p & 1, nt = p >> 1;
  int ml; int e = tile_lookup(ctrl, mt, &ml);
  if (e < 0) return;
  int tid = threadIdx.x, lane = tid & 63, wid = tid >> 6, wr = wid >> 1, wc = wid & 1;
  int rbase = ctrl[16 + e] + ml * 256;
  const int KST = (INTER / 64) / SPLITK;       // 22, even
  const unsigned char* Ab = (const unsigned char*)(act + (size_t)rbase * INTER) + (size_t)z * KST * 128;
  const unsigned char* Bw = (const unsigned char*)(w2 + (size_t)e * HIDDEN * INTER) + (size_t)z * KST * 256;
  int l3 = lane >> 3, l4 = lane >> 4, l15 = lane & 15;
  int swzA = ((lane & 7) ^ l3) << 4;

  unsigned aoff[4], boff[4];
#pragma unroll
  for (int i = 0; i < 4; i++) {
    int g = wid * 4 + i;
    aoff[i] = (unsigned)(g * 8 + l3) * (INTER * 2) + swzA;
  }
#pragma unroll
  for (int i = 0; i < 4; i++) {
    int r = (wid * 4 + i) * 4 + l4;
    boff[i] = (unsigned)(nt * 128 + r) * (INTER * 4) + ((l15 ^ (r & 15)) << 4);
  }

  f32x4 acc[4][4];
  f32x4 zero = {0.f, 0.f, 0.f, 0.f};
#pragma unroll
  for (int i = 0; i < 4; i++)
#pragma unroll
    for (int j = 0; j < 4; j++) acc[i][j] = zero;

#define STG2(kk, Ad, Bd) do {                                                        \
  _Pragma("unroll") for (int i = 0; i < 4; i++)                                      \
    gload16(Ab + (size_t)aoff[i] + (kk) * 128, &(Ad)[(wid * 4 + i) * 1024]);         \
  _Pragma("unroll") for (int i = 0; i < 4; i++)                                      \
    gload16(Bw + (size_t)boff[i] + (kk) * 256, &(Bd)[(wid * 4 + i) * 1024]);         \
} while (0)

#define CMP2(Ad, Bd) do {                                                            \
  _Pragma("unroll") for (int ks = 0; ks < 2; ++ks) {                                 \
    short8 a[4], b[4];                                                               \
    _Pragma("unroll") for (int mi = 0; mi < 4; mi++) {                               \
      int row = wr * 64 + mi * 16 + l15;                                             \
      int koff = ks * 64 + (l4 << 4);                                                \
      a[mi] = *(const short8*)&(Ad)[row * 128 + (koff ^ ((row & 7) << 4))];          \
    }                                                                                \
    _Pragma("unroll") for (int ni = 0; ni < 4; ni++) {                               \
      int r = wc * 64 + ni * 16 + l15;                                               \
      int c = ks * 8 + l4 * 2;                                                       \
      f32x4 lo = *(const f32x4*)&(Bd)[r * 256 + ((c ^ (r & 15)) << 4)];              \
      f32x4 hi = *(const f32x4*)&(Bd)[r * 256 + (((c + 1) ^ (r & 15)) << 4)];        \
      b[ni] = pack8(lo, hi);                                                         \
    }                                                                                \
    _Pragma("unroll") for (int mi = 0; mi < 4; mi++)                                 \
      _Pragma("unroll") for (int ni = 0; ni < 4; ni++)                               \
        acc[mi][ni] = __builtin_amdgcn_mfma_f32_16x16x32_bf16(a[mi], b[ni], acc[mi][ni], 0, 0, 0); \
  }                                                                                  \
} while (0)

  STG2(0, lds.A0, lds.Bf0);
  __syncthreads();
  for (int s = 0; s < KST; s += 2) {
    STG2(s + 1, lds.A1, lds.Bf1);
    CMP2(lds.A0, lds.Bf0);
    __syncthreads();
    if (s + 2 < KST) STG2(s + 2, lds.A0, lds.Bf0);
    CMP2(lds.A1, lds.Bf1);
    __syncthreads();
  }
#undef STG2
#undef CMP2

  float* P = Pb + (size_t)z * ROWCAP * HIDDEN;
#pragma unroll
  for (int mi = 0; mi < 4; mi++)
#pragma unroll
    for (int ni = 0; ni < 4; ni++) {
      int col = nt * 128 + wc * 64 + ni * 16 + l15;
#pragma unroll
      for (int r = 0; r < 4; r++) {
        int row = rbase + wr * 64 + mi * 16 + (l4 << 2) + r;
        P[(size_t)row * HIDDEN + col] = acc[mi][ni][r];
      }
    }
}

// ---------------- final: out[t] = w0*(P0+P1)[row0] + w1*(P0+P1)[row1] ----------------
__global__ void k_finish(const float* __restrict__ Pb,
                         const int* __restrict__ trow, const float* __restrict__ tkw,
                         float* __restrict__ out) {
  int t = blockIdx.x, c = threadIdx.x;
  const float* P0 = Pb;
  const float* P1 = Pb + (size_t)ROWCAP * HIDDEN;
  int r0 = trow[2 * t], r1 = trow[2 * t + 1];
  float w0 = tkw[2 * t], w1 = tkw[2 * t + 1];
  float4 a0 = ((const float4*)(P0 + (size_t)r0 * HIDDEN))[c];
  float4 b0 = ((const float4*)(P1 + (size_t)r0 * HIDDEN))[c];
  float4 a1 = ((const float4*)(P0 + (size_t)r1 * HIDDEN))[c];
  float4 b1 = ((const float4*)(P1 + (size_t)r1 * HIDDEN))[c];
  float4 o;
  o.x = w0 * (a0.x + b0.x) + w1 * (a1.x + b1.x);
  o.y = w0 * (a0.y + b0.y) + w1 * (a1.y + b1.y);
  o.z = w0 * (a0.z + b0.z) + w1 * (a1.z + b1.z);
  o.w = w0 * (a0.w + b0.w) + w1 * (a1.w + b1.w);
  ((float4*)(out + (size_t)t * HIDDEN))[c] = o;
}

extern "C" void kernel_launch(void* const* d_in, const int* in_sizes, int n_in,
                              void* d_out, int out_size, void* d_ws, size_t ws_size,
                              hipStream_t stream) {
  const float* x      = (const float*)d_in[0];
  const float* gating = (const float*)d_in[1];
  const float* w1     = (const float*)d_in[2];
  const float* w2     = (const float*)d_in[3];
  float* out = (float*)d_out;
  char* ws = (char*)d_ws;

  // ws layout (~98 MB; ws_size >= 178 MB confirmed)
  int*   ctrl = (int*)ws;                                   // cnt[8] cursor[8] base[8]
  int*   tkid = (int*)(ws + 4096);
  float* tkw  = (float*)(ws + 24576);
  int*   rtok = (int*)(ws + 45056);
  int*   trow = (int*)(ws + 73728);
  size_t off_Abf = 131072;
  size_t off_act = off_Abf + (size_t)ROWCAP * HIDDEN * 2;   // +12.58 MB
  size_t off_P   = off_act + (size_t)ROWCAP * INTER * 2;    // +34.60 MB
  unsigned short* Abf  = (unsigned short*)(ws + off_Abf);
  unsigned short* actb = (unsigned short*)(ws + off_act);
  float* Pb = (float*)(ws + off_P);                         // SPLITK x ROWCAP x HIDDEN f32

  hipMemsetAsync(ws, 0, 1024, stream);

  k_routing<<<TOKENS / 256, 256, 0, stream>>>(gating, ctrl, tkid, tkw);
  k_base<<<1, 64, 0, stream>>>(ctrl);
  k_fill<<<TOKENS / 256, 256, 0, stream>>>(ctrl, tkid, rtok, trow);
  k_gather<<<ROWCAP, 256, 0, stream>>>(x, ctrl, rtok, Abf);
  k_gemm1<<<NT1 * MT, 512, 0, stream>>>(w1, Abf, actb, ctrl);
  k_gemm2<<<NT2 * MT * SPLITK, 512, 0, stream>>>(w2, actb, Pb, ctrl);
  k_finish<<<TOKENS, 256, 0, stream>>>(Pb, trow, tkw, out);
}

// Round 9
// 257.377 us; speedup vs baseline: 1.0776x; 1.0776x over previous
//
#include <hip/hip_runtime.h>
#include <hip/hip_bf16.h>

#define TOKENS 2048
#define HIDDEN 1024
#define NEXP   8
#define INTER  2816
#define N1     5632      // 2*INTER
#define ROWCAP 6144      // 256-pad worst case: 4096 + 8*255 = 6136
#define MT     24        // ROWCAP/256 m-tiles
#define NT1    44        // gemm1 col tiles (64 gate + 64 up cols)
#define NT2    8         // gemm2 col tiles (128 out cols)
#define SPLITK 2         // gemm2 K-slices

typedef __attribute__((ext_vector_type(8))) short short8;   // 8 bf16 (MFMA A/B frag)
typedef __attribute__((ext_vector_type(4))) float f32x4;    // MFMA C/D frag

typedef unsigned int __attribute__((address_space(1))) as1_uint;
typedef unsigned int __attribute__((address_space(3))) as3_uint;

__device__ __forceinline__ void gload16(const void* g, void* l) {
  __builtin_amdgcn_global_load_lds((const as1_uint*)g, (as3_uint*)l, 16, 0, 0);
}

__device__ __forceinline__ unsigned short f2bf(float f) {  // RNE f32->bf16 (bit trick)
  unsigned u = __float_as_uint(f);
  u += 0x7fff + ((u >> 16) & 1);
  return (unsigned short)(u >> 16);
}
__device__ __forceinline__ float bf2f(unsigned short h) {
  return __uint_as_float(((unsigned)h) << 16);
}
__device__ __forceinline__ unsigned short bfs(float x) {   // fuses pairs -> v_cvt_pk_bf16_f32
  __hip_bfloat16 h = __float2bfloat16(x);
  return *reinterpret_cast<unsigned short*>(&h);
}
__device__ __forceinline__ short8 pack8(f32x4 lo, f32x4 hi) {
  short8 o;
  o[0] = (short)bfs(lo[0]); o[1] = (short)bfs(lo[1]); o[2] = (short)bfs(lo[2]); o[3] = (short)bfs(lo[3]);
  o[4] = (short)bfs(hi[0]); o[5] = (short)bfs(hi[1]); o[6] = (short)bfs(hi[2]); o[7] = (short)bfs(hi[3]);
  return o;
}

// raw barrier / counted waits (asm so the compiler can't drain vmcnt to 0 for us)
#define BARRIER() asm volatile("s_barrier" ::: "memory")
#define VMW4()    asm volatile("s_waitcnt vmcnt(4)" ::: "memory")
#define VMW0()    asm volatile("s_waitcnt vmcnt(0)" ::: "memory")
#define LGKM0()   asm volatile("s_waitcnt lgkmcnt(0)" ::: "memory")

// ---------------- routing: softmax->top2->renorm == sigmoid(l0-l1) ----------------
__global__ void k_routing(const float* __restrict__ gate, int* __restrict__ ctrl,
                          int* __restrict__ tkid, float* __restrict__ tkw) {
  int t = blockIdx.x * blockDim.x + threadIdx.x;
  if (t >= TOKENS) return;
  float l[8];
#pragma unroll
  for (int i = 0; i < 8; i++) l[i] = gate[t * 8 + i];
  int i0 = 0; float m0 = l[0];
#pragma unroll
  for (int i = 1; i < 8; i++) if (l[i] > m0) { m0 = l[i]; i0 = i; }
  int i1 = -1; float m1 = -3.4e38f;
#pragma unroll
  for (int i = 0; i < 8; i++) if (i != i0 && l[i] > m1) { m1 = l[i]; i1 = i; }
  float e  = __expf(m1 - m0);
  float w0 = 1.f / (1.f + e);
  float w1 = e / (1.f + e);
  tkid[2 * t] = i0; tkid[2 * t + 1] = i1;
  tkw[2 * t] = w0;  tkw[2 * t + 1] = w1;
  atomicAdd(&ctrl[i0], 1);
  atomicAdd(&ctrl[i1], 1);
}

// ctrl (ints): [0..7]=cnt  [8..15]=cursor  [16..23]=base (256-aligned prefix)
__global__ void k_base(int* ctrl) {
  if (threadIdx.x == 0) {
    int a = 0;
    for (int e = 0; e < 8; e++) { ctrl[16 + e] = a; a += ((ctrl[e] + 255) >> 8) << 8; }
  }
}

__global__ void k_fill(int* __restrict__ ctrl, const int* __restrict__ tkid,
                       int* __restrict__ rtok, int* __restrict__ trow) {
  int t = blockIdx.x * blockDim.x + threadIdx.x;
  if (t >= TOKENS) return;
#pragma unroll
  for (int k = 0; k < 2; k++) {
    int e = tkid[2 * t + k];
    int pos = atomicAdd(&ctrl[8 + e], 1);
    int row = ctrl[16 + e] + pos;
    rtok[row] = t;
    trow[2 * t + k] = row;
  }
}

// gather x rows (f32) -> bf16 A ordered by expert segment; zero padded rows
__global__ void k_gather(const float* __restrict__ x, const int* __restrict__ ctrl,
                         const int* __restrict__ rtok, unsigned short* __restrict__ Abf) {
  int row = blockIdx.x;
  int e = -1, local = 0;
  for (int i = 0; i < 8; i++) {
    int b = ctrl[16 + i], p = ((ctrl[i] + 255) >> 8) << 8;
    if (row >= b && row < b + p) { e = i; local = row - b; break; }
  }
  if (e < 0) return;
  int tid = threadIdx.x;
  unsigned short* dst = Abf + (size_t)row * HIDDEN;
  if (local < ctrl[e]) {
    int t = rtok[row];
    float4 v = ((const float4*)(x + (size_t)t * HIDDEN))[tid];
    ushort4 o; o.x = f2bf(v.x); o.y = f2bf(v.y); o.z = f2bf(v.z); o.w = f2bf(v.w);
    ((ushort4*)dst)[tid] = o;
  } else {
    ushort4 z; z.x = 0; z.y = 0; z.z = 0; z.w = 0;
    ((ushort4*)dst)[tid] = z;
  }
}

__device__ __forceinline__ int tile_lookup(const int* ctrl, int mt, int* ml) {
  int a0 = 0;
  for (int i = 0; i < 8; i++) {
    int pt = (ctrl[i] + 255) >> 8;
    if (mt < a0 + pt) { *ml = mt - a0; return i; }
    a0 += pt;
  }
  return -1;
}

// ======== shared phase helpers (BM=256, BN=128, BK=64; 512 thr; 8 waves 4m x 2n) ========
// A region: 256 rows x 128B bf16 (32K), 8-deep XOR swz on 16B blocks.
// B region: 128 rows x 256B f32 (32K), 16-deep XOR swz (f32 rows = 0 mod 32 banks).
// Per-tile vmcnt ledger (per wave, 4 A-loads + 4 B-loads per tile):
//   tile start: 4 outstanding (B(t+1));  P1 +4 (A(t+1)) -> 8;  P4 +4 (B(t+2)) -> 12;
//   tile end: VMW4 completes B(t+1),A(t+1), keeps B(t+2).  Tail: t+2>=NT -> VMW0.
// LGKM0 before P3-end and tile-end barriers: a wave's in-flight ds_reads must
// complete before any wave can overwrite that buffer (raw s_barrier doesn't drain lgkm).

#define STGA(kk, Ad, Abase) do {                                                      \
  _Pragma("unroll") for (int i_ = 0; i_ < 4; i_++)                                    \
    gload16((Abase) + (size_t)aoff[i_] + (size_t)(kk) * 128, &(Ad)[(wid * 4 + i_) * 1024]); \
} while (0)

#define STGB(kk, Bd, Bbase) do {                                                      \
  _Pragma("unroll") for (int i_ = 0; i_ < 4; i_++)                                    \
    gload16((Bbase) + (size_t)boff[i_] + (size_t)(kk) * 256, &(Bd)[(wid * 4 + i_) * 1024]); \
} while (0)

#define LDA_F(Ad, mi, ks)                                                              \
  (*(const short8*)&(Ad)[(wr * 64 + (mi) * 16 + l15) * 128 +                           \
     ((((ks) * 64 + (l4 << 4))) ^ ((l15 & 7) << 4))])

#define LDB_F(Bd, ni, ks, dst) do {                                                    \
  int r_ = wc * 64 + (ni) * 16 + l15;                                                  \
  int c_ = (ks) * 8 + l4 * 2;                                                          \
  f32x4 lo_ = *(const f32x4*)&(Bd)[r_ * 256 + ((c_ ^ (r_ & 15)) << 4)];                \
  f32x4 hi_ = *(const f32x4*)&(Bd)[r_ * 256 + (((c_ + 1) ^ (r_ & 15)) << 4)];          \
  dst = pack8(lo_, hi_);                                                               \
} while (0)

#define MFMA8(m0, a0_, a1_) do {                                                       \
  __builtin_amdgcn_s_setprio(1);                                                       \
  _Pragma("unroll") for (int ni_ = 0; ni_ < 4; ni_++)                                  \
    acc[(m0)][ni_] = __builtin_amdgcn_mfma_f32_16x16x32_bf16(a0_, bb[ni_], acc[(m0)][ni_], 0, 0, 0); \
  _Pragma("unroll") for (int ni_ = 0; ni_ < 4; ni_++)                                  \
    acc[(m0)+1][ni_] = __builtin_amdgcn_mfma_f32_16x16x32_bf16(a1_, bb[ni_], acc[(m0)+1][ni_], 0, 0, 0); \
  __builtin_amdgcn_s_setprio(0);                                                       \
} while (0)

// one K-tile: CA/CB = current buffers, NA = next A buffer; t = tile idx
#define KTILE(t, NTILES, CA, CB, NA, Abase, Bbase) do {                                 \
  if ((t) + 1 < (NTILES)) STGA((t) + 1, NA, Abase);                                     \
  { short8 a0 = LDA_F(CA, 0, 0), a1 = LDA_F(CA, 1, 0);                                  \
    LDB_F(CB, 0, 0, bb[0]); LDB_F(CB, 1, 0, bb[1]);                                     \
    LDB_F(CB, 2, 0, bb[2]); LDB_F(CB, 3, 0, bb[3]);                                     \
    MFMA8(0, a0, a1); }                                                                 \
  BARRIER();                                                                            \
  { short8 a2 = LDA_F(CA, 2, 0), a3 = LDA_F(CA, 3, 0);                                  \
    MFMA8(2, a2, a3); }                                                                 \
  BARRIER();                                                                            \
  { short8 a0 = LDA_F(CA, 0, 1), a1 = LDA_F(CA, 1, 1);                                  \
    LDB_F(CB, 0, 1, bb[0]); LDB_F(CB, 1, 1, bb[1]);                                     \
    LDB_F(CB, 2, 1, bb[2]); LDB_F(CB, 3, 1, bb[3]);                                     \
    MFMA8(0, a0, a1); }                                                                 \
  LGKM0();                                                                              \
  BARRIER();                                                                            \
  { short8 a2 = LDA_F(CA, 2, 1), a3 = LDA_F(CA, 3, 1);                                  \
    if ((t) + 2 < (NTILES)) STGB((t) + 2, CB, Bbase);                                   \
    MFMA8(2, a2, a3); }                                                                 \
  if ((t) + 2 < (NTILES)) { VMW4(); } else { VMW0(); }                                  \
  LGKM0();                                                                              \
  BARRIER();                                                                            \
} while (0)

// ============ GEMM1: h = A*w1^T (256x[64g|64u]), 4-phase counted-vmcnt pipeline ============
__global__ __launch_bounds__(512, 2) void k_gemm1(const float* __restrict__ w1,
    const unsigned short* __restrict__ Abf, unsigned short* __restrict__ act,
    const int* __restrict__ ctrl) {
  union __align__(16) LdsU {
    struct { unsigned char A0[32768]; unsigned char B0[32768];
             unsigned char A1[32768]; unsigned char B1[32768]; } st;
    unsigned short hb[256 * 132];   // 67584 B (used only after final VMW0+LGKM0+BARRIER)
  };
  __shared__ LdsU lds;
  int bid = blockIdx.x;                        // 1056 % 8 == 0, bijective XCD swizzle
  int wg = (bid & 7) * (NT1 * MT / 8) + (bid >> 3);
  int nt = wg / MT, mt = wg % MT;              // nt-major: XCD chunk shares B panel
  int ml; int e = tile_lookup(ctrl, mt, &ml);
  if (e < 0) return;
  int tid = threadIdx.x, lane = tid & 63, wid = tid >> 6, wr = wid >> 1, wc = wid & 1;
  int rbase = ctrl[16 + e] + ml * 256;
  const unsigned char* Ab = (const unsigned char*)(Abf + (size_t)rbase * HIDDEN);
  const unsigned char* Bw = (const unsigned char*)(w1 + (size_t)e * N1 * HIDDEN);
  int l3 = lane >> 3, l4 = lane >> 4, l15 = lane & 15;
  int swzA = ((lane & 7) ^ l3) << 4;

  unsigned aoff[4], boff[4];
#pragma unroll
  for (int i = 0; i < 4; i++) {
    int g = wid * 4 + i;                       // 32 groups of 8 A-rows (0..255)
    aoff[i] = (unsigned)(g * 8 + l3) * (HIDDEN * 2) + swzA;
  }
#pragma unroll
  for (int i = 0; i < 4; i++) {
    int r = (wid * 4 + i) * 4 + l4;            // 32 groups of 4 f32 B-rows (0..127)
    int grow = (r < 64) ? nt * 64 + r : INTER + nt * 64 + (r - 64);
    boff[i] = (unsigned)grow * (HIDDEN * 4) + ((l15 ^ (r & 15)) << 4);  // pre-swizzled src
  }

  f32x4 acc[4][4];
  f32x4 zero = {0.f, 0.f, 0.f, 0.f};
#pragma unroll
  for (int i = 0; i < 4; i++)
#pragma unroll
    for (int j = 0; j < 4; j++) acc[i][j] = zero;
  short8 bb[4];

  const int NS = HIDDEN / 64;                  // 16, even
  // prologue: A(0), B(0), B(1) -> 12 outstanding; drain to 4 (A0,B0 done, B1 in flight)
  STGA(0, lds.st.A0, Ab);
  STGB(0, lds.st.B0, Bw);
  STGB(1, lds.st.B1, Bw);
  VMW4();
  BARRIER();
  for (int t = 0; t < NS; t += 2) {
    KTILE(t,     NS, lds.st.A0, lds.st.B0, lds.st.A1, Ab, Bw);
    KTILE(t + 1, NS, lds.st.A1, lds.st.B1, lds.st.A0, Ab, Bw);
  }

  // epilogue: h -> LDS bf16, then act = silu(gate)*up -> global
#pragma unroll
  for (int mi = 0; mi < 4; mi++)
#pragma unroll
    for (int ni = 0; ni < 4; ni++)
#pragma unroll
      for (int r = 0; r < 4; r++) {
        int row = wr * 64 + mi * 16 + (l4 << 2) + r;   // C/D: row=(lane>>4)*4+reg
        int col = wc * 64 + ni * 16 + l15;             //      col=lane&15
        lds.hb[row * 132 + col] = f2bf(acc[mi][ni][r]);
      }
  __syncthreads();
  {
    int r = tid >> 1, ch = (tid & 1) * 32;
    unsigned short* orow = act + (size_t)(rbase + r) * INTER + nt * 64 + ch;
    const unsigned short* hrow = &lds.hb[r * 132];
#pragma unroll
    for (int j = 0; j < 32; j += 4) {
      ushort4 o;
#pragma unroll
      for (int q = 0; q < 4; q++) {
        float g = bf2f(hrow[ch + j + q]);
        float u = bf2f(hrow[64 + ch + j + q]);
        float s = g / (1.f + __expf(-g));
        ((unsigned short*)&o)[q] = f2bf(s * u);
      }
      *(ushort4*)(orow + j) = o;
    }
  }
}

// ============ GEMM2: same pipeline, split-K, plain f32 stores ============
__global__ __launch_bounds__(512, 2) void k_gemm2(const float* __restrict__ w2,
    const unsigned short* __restrict__ act, float* __restrict__ Pb,
    const int* __restrict__ ctrl) {
  struct __align__(16) Lds2 { unsigned char A0[32768]; unsigned char B0[32768];
                              unsigned char A1[32768]; unsigned char B1[32768]; };
  __shared__ Lds2 lds;
  int bid = blockIdx.x;                        // 384 % 8 == 0
  int wg = (bid & 7) * (NT2 * MT * SPLITK / 8) + (bid >> 3);
  int mt = wg % MT;
  int p = wg / MT;                             // 0..15
  int z = p & 1, nt = p >> 1;
  int ml; int e = tile_lookup(ctrl, mt, &ml);
  if (e < 0) return;
  int tid = threadIdx.x, lane = tid & 63, wid = tid >> 6, wr = wid >> 1, wc = wid & 1;
  int rbase = ctrl[16 + e] + ml * 256;
  const int KST = (INTER / 64) / SPLITK;       // 22, even
  const unsigned char* Ab = (const unsigned char*)(act + (size_t)rbase * INTER) + (size_t)z * KST * 128;
  const unsigned char* Bw = (const unsigned char*)(w2 + (size_t)e * HIDDEN * INTER) + (size_t)z * KST * 256;
  int l3 = lane >> 3, l4 = lane >> 4, l15 = lane & 15;
  int swzA = ((lane & 7) ^ l3) << 4;

  unsigned aoff[4], boff[4];
#pragma unroll
  for (int i = 0; i < 4; i++) {
    int g = wid * 4 + i;
    aoff[i] = (unsigned)(g * 8 + l3) * (INTER * 2) + swzA;
  }
#pragma unroll
  for (int i = 0; i < 4; i++) {
    int r = (wid * 4 + i) * 4 + l4;
    boff[i] = (unsigned)(nt * 128 + r) * (INTER * 4) + ((l15 ^ (r & 15)) << 4);
  }

  f32x4 acc[4][4];
  f32x4 zero = {0.f, 0.f, 0.f, 0.f};
#pragma unroll
  for (int i = 0; i < 4; i++)
#pragma unroll
    for (int j = 0; j < 4; j++) acc[i][j] = zero;
  short8 bb[4];

  STGA(0, lds.A0, Ab);
  STGB(0, lds.B0, Bw);
  STGB(1, lds.B1, Bw);
  VMW4();
  BARRIER();
  for (int t = 0; t < KST; t += 2) {
    KTILE(t,     KST, lds.A0, lds.B0, lds.A1, Ab, Bw);
    KTILE(t + 1, KST, lds.A1, lds.B1, lds.A0, Ab, Bw);
  }

  float* P = Pb + (size_t)z * ROWCAP * HIDDEN;
#pragma unroll
  for (int mi = 0; mi < 4; mi++)
#pragma unroll
    for (int ni = 0; ni < 4; ni++) {
      int col = nt * 128 + wc * 64 + ni * 16 + l15;
#pragma unroll
      for (int r = 0; r < 4; r++) {
        int row = rbase + wr * 64 + mi * 16 + (l4 << 2) + r;
        P[(size_t)row * HIDDEN + col] = acc[mi][ni][r];
      }
    }
}

// ---------------- final: out[t] = w0*(P0+P1)[row0] + w1*(P0+P1)[row1] ----------------
__global__ void k_finish(const float* __restrict__ Pb,
                         const int* __restrict__ trow, const float* __restrict__ tkw,
                         float* __restrict__ out) {
  int t = blockIdx.x, c = threadIdx.x;
  const float* P0 = Pb;
  const float* P1 = Pb + (size_t)ROWCAP * HIDDEN;
  int r0 = trow[2 * t], r1 = trow[2 * t + 1];
  float w0 = tkw[2 * t], w1 = tkw[2 * t + 1];
  float4 a0 = ((const float4*)(P0 + (size_t)r0 * HIDDEN))[c];
  float4 b0 = ((const float4*)(P1 + (size_t)r0 * HIDDEN))[c];
  float4 a1 = ((const float4*)(P0 + (size_t)r1 * HIDDEN))[c];
  float4 b1 = ((const float4*)(P1 + (size_t)r1 * HIDDEN))[c];
  float4 o;
  o.x = w0 * (a0.x + b0.x) + w1 * (a1.x + b1.x);
  o.y = w0 * (a0.y + b0.y) + w1 * (a1.y + b1.y);
  o.z = w0 * (a0.z + b0.z) + w1 * (a1.z + b1.z);
  o.w = w0 * (a0.w + b0.w) + w1 * (a1.w + b1.w);
  ((float4*)(out + (size_t)t * HIDDEN))[c] = o;
}

extern "C" void kernel_launch(void* const* d_in, const int* in_sizes, int n_in,
                              void* d_out, int out_size, void* d_ws, size_t ws_size,
                              hipStream_t stream) {
  const float* x      = (const float*)d_in[0];
  const float* gating = (const float*)d_in[1];
  const float* w1     = (const float*)d_in[2];
  const float* w2     = (const float*)d_in[3];
  float* out = (float*)d_out;
  char* ws = (char*)d_ws;

  // ws layout (~98 MB; ws_size >= 178 MB confirmed)
  int*   ctrl = (int*)ws;                                   // cnt[8] cursor[8] base[8]
  int*   tkid = (int*)(ws + 4096);
  float* tkw  = (float*)(ws + 24576);
  int*   rtok = (int*)(ws + 45056);
  int*   trow = (int*)(ws + 73728);
  size_t off_Abf = 131072;
  size_t off_act = off_Abf + (size_t)ROWCAP * HIDDEN * 2;   // +12.58 MB
  size_t off_P   = off_act + (size_t)ROWCAP * INTER * 2;    // +34.60 MB
  unsigned short* Abf  = (unsigned short*)(ws + off_Abf);
  unsigned short* actb = (unsigned short*)(ws + off_act);
  float* Pb = (float*)(ws + off_P);                         // SPLITK x ROWCAP x HIDDEN f32

  hipMemsetAsync(ws, 0, 1024, stream);

  k_routing<<<TOKENS / 256, 256, 0, stream>>>(gating, ctrl, tkid, tkw);
  k_base<<<1, 64, 0, stream>>>(ctrl);
  k_fill<<<TOKENS / 256, 256, 0, stream>>>(ctrl, tkid, rtok, trow);
  k_gather<<<ROWCAP, 256, 0, stream>>>(x, ctrl, rtok, Abf);
  k_gemm1<<<NT1 * MT, 512, 0, stream>>>(w1, Abf, actb, ctrl);
  k_gemm2<<<NT2 * MT * SPLITK, 512, 0, stream>>>(w2, actb, Pb, ctrl);
  k_finish<<<TOKENS, 256, 0, stream>>>(Pb, trow, tkw, out);
}